// Round 12
// baseline (759.499 us; speedup 1.0000x reference)
//
#include <hip/hip_runtime.h>
#include <hip/hip_bf16.h>
#include <math.h>

#define B 8
#define L 513
#define D 512
#define H 8
#define HS 64
#define V 513
#define NL 6
#define BL (B * L)          // 4104
#define LP 576              // padded L for vT
#define EPS 1e-5f

typedef __attribute__((ext_vector_type(8))) short bf16x8;   // 8 bf16 (4 VGPRs)
typedef __attribute__((ext_vector_type(4))) float f32x4;    // MFMA accumulator

__device__ inline ushort f2b(float f) {
    __hip_bfloat16 h = __float2bfloat16(f);
    return *reinterpret_cast<ushort*>(&h);
}

__device__ inline uint4 pack8(float4 a, float4 b) {
    union { ushort u[8]; uint4 v; } r;
    r.u[0] = f2b(a.x); r.u[1] = f2b(a.y); r.u[2] = f2b(a.z); r.u[3] = f2b(a.w);
    r.u[4] = f2b(b.x); r.u[5] = f2b(b.y); r.u[6] = f2b(b.z); r.u[7] = f2b(b.w);
    return r.v;
}

// ---------------------------------------------------------------------------
// embed: h[row] = emb[x[row]] + pos[row%L]   (fp32, 4 rows/block)
// ---------------------------------------------------------------------------
__global__ __launch_bounds__(256) void embed4_k(const int* __restrict__ xi,
                                                const float* __restrict__ emb,
                                                const float* __restrict__ pos,
                                                float* __restrict__ h)
{
    const int wave = threadIdx.x >> 6, lane = threadIdx.x & 63;
    const int row = blockIdx.x * 4 + wave;
    const int l = row % L;
    const int tok = xi[row];
    const float* er = emb + (size_t)tok * D + lane * 8;
    const float* pr = pos + (size_t)l * D + lane * 8;
    float4 e0 = *(const float4*)er, e1 = *(const float4*)(er + 4);
    float4 p0 = *(const float4*)pr, p1 = *(const float4*)(pr + 4);
    float* hr = h + (size_t)row * D + lane * 8;
    *(float4*)hr       = make_float4(e0.x + p0.x, e0.y + p0.y, e0.z + p0.z, e0.w + p0.w);
    *(float4*)(hr + 4) = make_float4(e1.x + p1.x, e1.y + p1.y, e1.z + p1.z, e1.w + p1.w);
}

// ---------------------------------------------------------------------------
// cvt_qkv: fold ln1 gamma into W, transpose, and compute LN column constants
//   Wp[i][n][d] = g1[d] * W[i][h][d][e],  n = sel*512 + h*64 + e
//   s1[n] = sum_d g1[d] W[d][e],  s2[n] = sum_d b1[d] W[d][e]
// grid (NL*H, 3), 256 threads; block reads full 512 x 64 panel.
// ---------------------------------------------------------------------------
__global__ __launch_bounds__(256) void cvt_qkv_k(const float* __restrict__ Wq,
                                                 const float* __restrict__ Wk,
                                                 const float* __restrict__ Wv,
                                                 const float* __restrict__ g1all,
                                                 const float* __restrict__ b1all,
                                                 ushort* __restrict__ Wp,
                                                 float* __restrict__ s1,
                                                 float* __restrict__ s2)
{
    const int i = blockIdx.x / H, h = blockIdx.x % H;
    const int sel = blockIdx.y;
    const float* W = (sel == 0) ? Wq : (sel == 1) ? Wk : Wv;
    const float* src = W + ((size_t)i * H + h) * D * HS;
    const float* g1 = g1all + (size_t)i * D;
    const float* b1 = b1all + (size_t)i * D;

    __shared__ float T[64][65];
    __shared__ float sP1[16][64];
    __shared__ float sP2[16][64];

    const int tid = threadIdx.x;
    const int equad = (tid & 15) * 4;    // column quad (e)
    const int jrow  = tid >> 4;          // row group 0..15
    float p1[4] = {0, 0, 0, 0}, p2[4] = {0, 0, 0, 0};

    ushort* dst = Wp + (size_t)i * 1536 * 512 + (size_t)(sel * 512 + h * 64) * 512;

    for (int dc = 0; dc < 8; ++dc) {
#pragma unroll
        for (int it = 0; it < 4; ++it) {
            int r = jrow + it * 16;                 // d-local
            float4 f = *(const float4*)(src + (size_t)(dc * 64 + r) * HS + equad);
            T[r][equad] = f.x; T[r][equad + 1] = f.y;
            T[r][equad + 2] = f.z; T[r][equad + 3] = f.w;
            float gg = g1[dc * 64 + r], bb = b1[dc * 64 + r];
            p1[0] += gg * f.x; p1[1] += gg * f.y; p1[2] += gg * f.z; p1[3] += gg * f.w;
            p2[0] += bb * f.x; p2[1] += bb * f.y; p2[2] += bb * f.z; p2[3] += bb * f.w;
        }
        __syncthreads();
#pragma unroll
        for (int it = 0; it < 4; ++it) {
            int e = jrow + it * 16;
            int d4 = equad;
            float4 gq = *(const float4*)(g1 + dc * 64 + d4);
            ushort4 u;
            u.x = f2b(T[d4][e] * gq.x);     u.y = f2b(T[d4 + 1][e] * gq.y);
            u.z = f2b(T[d4 + 2][e] * gq.z); u.w = f2b(T[d4 + 3][e] * gq.w);
            *(ushort4*)(dst + (size_t)e * 512 + dc * 64 + d4) = u;
        }
        __syncthreads();
    }

#pragma unroll
    for (int q = 0; q < 4; ++q) { sP1[jrow][equad + q] = p1[q]; sP2[jrow][equad + q] = p2[q]; }
    __syncthreads();
    if (tid < 64) {
        float a1 = 0.f, a2 = 0.f;
#pragma unroll
        for (int j = 0; j < 16; ++j) { a1 += sP1[j][tid]; a2 += sP2[j][tid]; }
        size_t n = (size_t)i * 1536 + sel * 512 + h * 64 + tid;
        s1[n] = a1; s2[n] = a2;
    }
}

// ---------------------------------------------------------------------------
// cvt_mlp: fold ln2 gamma; Wt[i][n][k] = g2[k]*mlp_W[i][k][n]; s1m/s2m per col.
// grid (8, NL): nt = col-tile, i = layer. Block reads 512 x 64 panel.
// ---------------------------------------------------------------------------
__global__ __launch_bounds__(256) void cvt_mlp_k(const float* __restrict__ Wm,
                                                 const float* __restrict__ g2all,
                                                 const float* __restrict__ b2all,
                                                 ushort* __restrict__ Wt,
                                                 float* __restrict__ s1,
                                                 float* __restrict__ s2)
{
    const int nt = blockIdx.x, i = blockIdx.y;
    const float* src = Wm + (size_t)i * D * D + nt * 64;
    const float* g2 = g2all + (size_t)i * D;
    const float* b2 = b2all + (size_t)i * D;

    __shared__ float T[64][65];
    __shared__ float sP1[16][64];
    __shared__ float sP2[16][64];

    const int tid = threadIdx.x;
    const int equad = (tid & 15) * 4;    // n-local quad
    const int jrow  = tid >> 4;
    float p1[4] = {0, 0, 0, 0}, p2[4] = {0, 0, 0, 0};

    ushort* dst = Wt + (size_t)i * D * D + (size_t)(nt * 64) * D;

    for (int kt = 0; kt < 8; ++kt) {
#pragma unroll
        for (int it = 0; it < 4; ++it) {
            int r = jrow + it * 16;                 // k-local
            float4 f = *(const float4*)(src + (size_t)(kt * 64 + r) * D + equad);
            T[r][equad] = f.x; T[r][equad + 1] = f.y;
            T[r][equad + 2] = f.z; T[r][equad + 3] = f.w;
            float gg = g2[kt * 64 + r], bb = b2[kt * 64 + r];
            p1[0] += gg * f.x; p1[1] += gg * f.y; p1[2] += gg * f.z; p1[3] += gg * f.w;
            p2[0] += bb * f.x; p2[1] += bb * f.y; p2[2] += bb * f.z; p2[3] += bb * f.w;
        }
        __syncthreads();
#pragma unroll
        for (int it = 0; it < 4; ++it) {
            int e = jrow + it * 16;                 // n-local
            int k4 = equad;
            float4 gq = *(const float4*)(g2 + kt * 64 + k4);
            ushort4 u;
            u.x = f2b(T[k4][e] * gq.x);     u.y = f2b(T[k4 + 1][e] * gq.y);
            u.z = f2b(T[k4 + 2][e] * gq.z); u.w = f2b(T[k4 + 3][e] * gq.w);
            *(ushort4*)(dst + (size_t)e * D + kt * 64 + k4) = u;
        }
        __syncthreads();
    }

#pragma unroll
    for (int q = 0; q < 4; ++q) { sP1[jrow][equad + q] = p1[q]; sP2[jrow][equad + q] = p2[q]; }
    __syncthreads();
    if (tid < 64) {
        float a1 = 0.f, a2 = 0.f;
#pragma unroll
        for (int j = 0; j < 16; ++j) { a1 += sP1[j][tid]; a2 += sP2[j][tid]; }
        size_t n = (size_t)i * 512 + nt * 64 + tid;
        s1[n] = a1; s2[n] = a2;
    }
}

// fc_W[k][n] (512,513) -> Wt[n][k] bf16, n padded to 576 with zeros (no LN)
__global__ __launch_bounds__(256) void cvt_fc_k(const float* __restrict__ Wf,
                                                ushort* __restrict__ Wt)
{
    const int nt = blockIdx.x, kt = blockIdx.y;     // 9 x 8
    __shared__ float T[64][65];
    const int tid = threadIdx.x;
#pragma unroll
    for (int it = 0; it < 4; ++it) {
        int idx = tid + it * 256;
        int r = idx >> 4, e4 = (idx & 15) * 4;
#pragma unroll
        for (int j = 0; j < 4; ++j) {
            int n = nt * 64 + e4 + j;
            T[r][e4 + j] = (n < V) ? Wf[(size_t)(kt * 64 + r) * V + n] : 0.f;
        }
    }
    __syncthreads();
    ushort* dst = Wt + (size_t)(nt * 64) * 512 + kt * 64;
#pragma unroll
    for (int it = 0; it < 4; ++it) {
        int idx = tid + it * 256;
        int e = idx >> 4, k4 = (idx & 15) * 4;
        ushort4 u;
        u.x = f2b(T[k4][e]); u.y = f2b(T[k4 + 1][e]);
        u.z = f2b(T[k4 + 2][e]); u.w = f2b(T[k4 + 3][e]);
        *(ushort4*)(dst + (size_t)e * 512 + k4) = u;
    }
}

// ---------------------------------------------------------------------------
// bf16 MFMA GEMM with ALGEBRAIC LN FUSION (modes 0,1,3):
//   xn@W = rs_r*(x@(g.W) - mu_r*s1_c) + s2_c  — weights pre-folded with g,
//   per-row mu/rs accumulated for free during fp32 A-staging, applied in
//   epilogue. R11 loop structure (single buffer, 2 barriers/K-step) + XOR
//   bank swizzle on linear [64x64] LDS.
// MODE 0: QKV (N=1536): A=h fp32; q/k bf16 (B,H,L,HS); v bf16 T (B,H,HS,LP).
// MODE 1: MLP (N=512):  A=h fp32; o0(fp32 h_next) = gelu(ln(acc)+bias) + o1.
// MODE 3: MLP final:    as MODE 1 but o0 is bf16 (hb for FC).
// MODE 2: FC  (N=576p): A=hb bf16 (no LN); o0 fp32 [r*V+c] = acc + bias[c].
// ---------------------------------------------------------------------------
template <int MODE>
__global__ __launch_bounds__(256) void mgemm_k(const void* __restrict__ Av,
                                               const ushort* __restrict__ Bt,
                                               const float* __restrict__ s1,
                                               const float* __restrict__ s2,
                                               const float* __restrict__ bias,
                                               void* __restrict__ o0,
                                               void* __restrict__ o1,
                                               void* __restrict__ o2)
{
    constexpr bool LNF = (MODE != 2);
    __shared__ ushort As[64 * 64];
    __shared__ ushort Bs[64 * 64];
    __shared__ float sMu[64];
    __shared__ float sRs[64];

    const int tid  = threadIdx.x;
    const int wave = tid >> 6, lane = tid & 63;
    const int row0 = blockIdx.y * 64;
    const int col0 = blockIdx.x * 64;
    const int wr = (wave >> 1) * 32, wc = (wave & 1) * 32;
    const int frow = lane & 15;
    const int kb   = lane >> 4;

    const int sr0 = tid >> 3, skc = tid & 7;
    const int sr1 = (tid + 256) >> 3;
    const int ss0 = (skc ^ (sr0 & 7)) * 8;
    const int ss1 = (skc ^ (sr1 & 7)) * 8;

    float st_s0 = 0.f, st_q0 = 0.f, st_s1 = 0.f, st_q1 = 0.f;

    f32x4 acc[2][2] = {};

    for (int k0 = 0; k0 < 512; k0 += 64) {
        if constexpr (LNF) {
            const float* hA = (const float*)Av;
            float4 f0 = {0, 0, 0, 0}, f1 = {0, 0, 0, 0};
            if (row0 + sr0 < BL) {
                const float* p = hA + (size_t)(row0 + sr0) * 512 + k0 + skc * 8;
                f0 = ((const float4*)p)[0]; f1 = ((const float4*)p)[1];
            }
            st_s0 += f0.x + f0.y + f0.z + f0.w + f1.x + f1.y + f1.z + f1.w;
            st_q0 += f0.x*f0.x + f0.y*f0.y + f0.z*f0.z + f0.w*f0.w
                   + f1.x*f1.x + f1.y*f1.y + f1.z*f1.z + f1.w*f1.w;
            *(uint4*)&As[sr0 * 64 + ss0] = pack8(f0, f1);
            float4 g0 = {0, 0, 0, 0}, g1 = {0, 0, 0, 0};
            if (row0 + sr1 < BL) {
                const float* p = hA + (size_t)(row0 + sr1) * 512 + k0 + skc * 8;
                g0 = ((const float4*)p)[0]; g1 = ((const float4*)p)[1];
            }
            st_s1 += g0.x + g0.y + g0.z + g0.w + g1.x + g1.y + g1.z + g1.w;
            st_q1 += g0.x*g0.x + g0.y*g0.y + g0.z*g0.z + g0.w*g0.w
                   + g1.x*g1.x + g1.y*g1.y + g1.z*g1.z + g1.w*g1.w;
            *(uint4*)&As[sr1 * 64 + ss1] = pack8(g0, g1);
        } else {
            const ushort* A = (const ushort*)Av;
            uint4 av = make_uint4(0u, 0u, 0u, 0u);
            if (row0 + sr0 < BL)
                av = *(const uint4*)(A + (size_t)(row0 + sr0) * 512 + k0 + skc * 8);
            *(uint4*)&As[sr0 * 64 + ss0] = av;
            av = make_uint4(0u, 0u, 0u, 0u);
            if (row0 + sr1 < BL)
                av = *(const uint4*)(A + (size_t)(row0 + sr1) * 512 + k0 + skc * 8);
            *(uint4*)&As[sr1 * 64 + ss1] = av;
        }
        {
            uint4 bv = *(const uint4*)(Bt + (size_t)(col0 + sr0) * 512 + k0 + skc * 8);
            *(uint4*)&Bs[sr0 * 64 + ss0] = bv;
            bv = *(const uint4*)(Bt + (size_t)(col0 + sr1) * 512 + k0 + skc * 8);
            *(uint4*)&Bs[sr1 * 64 + ss1] = bv;
        }
        __syncthreads();
#pragma unroll
        for (int ks = 0; ks < 2; ++ks) {
            bf16x8 a[2], b[2];
            const int g = ks * 4 + kb;
#pragma unroll
            for (int f = 0; f < 2; ++f) {
                const int ra_ = wr + f * 16 + frow;
                a[f] = *(const bf16x8*)&As[ra_ * 64 + ((g ^ (ra_ & 7)) * 8)];
                const int rb_ = wc + f * 16 + frow;
                b[f] = *(const bf16x8*)&Bs[rb_ * 64 + ((g ^ (rb_ & 7)) * 8)];
            }
#pragma unroll
            for (int fi = 0; fi < 2; ++fi)
#pragma unroll
                for (int fj = 0; fj < 2; ++fj)
                    acc[fi][fj] = __builtin_amdgcn_mfma_f32_16x16x32_bf16(
                        a[fi], b[fj], acc[fi][fj], 0, 0, 0);
        }
        __syncthreads();
    }

    if constexpr (LNF) {
#pragma unroll
        for (int off = 1; off < 8; off <<= 1) {
            st_s0 += __shfl_xor(st_s0, off); st_q0 += __shfl_xor(st_q0, off);
            st_s1 += __shfl_xor(st_s1, off); st_q1 += __shfl_xor(st_q1, off);
        }
        if (skc == 0) {
            float mu0 = st_s0 * (1.f / 512);
            sMu[sr0] = mu0; sRs[sr0] = rsqrtf(st_q0 * (1.f / 512) - mu0 * mu0 + EPS);
            float mu1 = st_s1 * (1.f / 512);
            sMu[sr1] = mu1; sRs[sr1] = rsqrtf(st_q1 * (1.f / 512) - mu1 * mu1 + EPS);
        }
        __syncthreads();
    }

    // C frag layout: col = lane&15, row = (lane>>4)*4 + reg
    const int rbase = row0 + wr + (lane >> 4) * 4;
    const int cbase = col0 + wc + (lane & 15);
#pragma unroll
    for (int fi = 0; fi < 2; ++fi) {
#pragma unroll
        for (int fj = 0; fj < 2; ++fj) {
            const int c = cbase + fj * 16;
            float s1c = 0.f, s2c = 0.f;
            if constexpr (LNF) { s1c = s1[c]; s2c = s2[c]; }
#pragma unroll
            for (int rg = 0; rg < 4; ++rg) {
                const int r = rbase + fi * 16 + rg;
                if (r >= BL) continue;
                float val = acc[fi][fj][rg];
                if constexpr (LNF) {
                    const int rl = wr + (lane >> 4) * 4 + fi * 16 + rg;
                    val = sRs[rl] * (val - sMu[rl] * s1c) + s2c;
                }
                if (MODE == 0) {
                    int buf = c >> 9, cc = c & 511;
                    int b_ = r / L, l = r % L;
                    int head = cc >> 6, e = cc & 63;
                    int bh = b_ * H + head;
                    if (buf == 0)
                        ((ushort*)o0)[((size_t)bh * L + l) * HS + e] = f2b(val);
                    else if (buf == 1)
                        ((ushort*)o1)[((size_t)bh * L + l) * HS + e] = f2b(val);
                    else
                        ((ushort*)o2)[((size_t)bh * HS + e) * LP + l] = f2b(val);
                } else if (MODE == 1) {
                    float xv = val + bias[c];
                    float gl = 0.5f * xv * (1.f + erff(xv * 0.70710678118654752f));
                    ((float*)o0)[(size_t)r * D + c] = gl + ((const float*)o1)[(size_t)r * D + c];
                } else if (MODE == 3) {
                    float xv = val + bias[c];
                    float gl = 0.5f * xv * (1.f + erff(xv * 0.70710678118654752f));
                    float res = ((const float*)o1)[(size_t)r * D + c];
                    ((ushort*)o0)[(size_t)r * D + c] = f2b(gl + res);
                } else {
                    if (c < V) ((float*)o0)[(size_t)r * V + c] = val + bias[c];
                }
            }
        }
    }
}

// ---------------------------------------------------------------------------
// MFMA flash attention (unchanged from R11 — verified at 543 us).
// ---------------------------------------------------------------------------
__global__ __launch_bounds__(256) void fattn_k(const ushort* __restrict__ qb,
                                               const ushort* __restrict__ kb,
                                               const ushort* __restrict__ vT,
                                               float* __restrict__ hbuf)
{
    __shared__ ushort Qs[64 * 64];
    __shared__ ushort Ks[64 * 64];
    __shared__ ushort Vs[64 * 64];   // [e][kv]
    __shared__ ushort Ps[64][72];

    const int bx  = blockIdx.x;
    const int bh  = bx / 9;
    const int qt  = 8 - (bx % 9);        // big tiles dispatched first
    const int q0  = qt * 64;
    const int tid = threadIdx.x;
    const int wave = tid >> 6, lane = tid & 63;
    const int lg = lane >> 4, li = lane & 15;
    const int wq = wave * 16;

    const int sr0 = tid >> 3, skc = tid & 7;
    const int sr1 = (tid + 256) >> 3;
    const int ss0 = (skc ^ (sr0 & 7)) * 8;
    const int ss1 = (skc ^ (sr1 & 7)) * 8;

    // ---- stage Q (swizzled) ----
    {
        int qr = q0 + sr0;
        uint4 v = make_uint4(0u, 0u, 0u, 0u);
        if (qr < L) v = *(const uint4*)(qb + ((size_t)bh * L + qr) * HS + skc * 8);
        *(uint4*)&Qs[sr0 * 64 + ss0] = v;
        qr = q0 + sr1;
        v = make_uint4(0u, 0u, 0u, 0u);
        if (qr < L) v = *(const uint4*)(qb + ((size_t)bh * L + qr) * HS + skc * 8);
        *(uint4*)&Qs[sr1 * 64 + ss1] = v;
    }

    const short one_b = (short)0x3F80;                 // bf16 1.0
    const bf16x8 ones = { one_b, one_b, one_b, one_b, one_b, one_b, one_b, one_b };

    f32x4 accO[4] = {};
    f32x4 accL = {};

    const int n_mt = qt + 1;
    uint4 kr[2], vr[2];

    auto loadKV = [&](int t) {
        int mr = t * 64 + sr0;
        kr[0] = make_uint4(0u, 0u, 0u, 0u);
        if (mr < L) kr[0] = *(const uint4*)(kb + ((size_t)bh * L + mr) * HS + skc * 8);
        vr[0] = *(const uint4*)(vT + ((size_t)bh * HS + sr0) * LP + t * 64 + skc * 8);
        mr = t * 64 + sr1;
        kr[1] = make_uint4(0u, 0u, 0u, 0u);
        if (mr < L) kr[1] = *(const uint4*)(kb + ((size_t)bh * L + mr) * HS + skc * 8);
        vr[1] = *(const uint4*)(vT + ((size_t)bh * HS + sr1) * LP + t * 64 + skc * 8);
    };
    auto writeKV = [&]() {
        *(uint4*)&Ks[sr0 * 64 + ss0] = kr[0];
        *(uint4*)&Vs[sr0 * 64 + ss0] = vr[0];
        *(uint4*)&Ks[sr1 * 64 + ss1] = kr[1];
        *(uint4*)&Vs[sr1 * 64 + ss1] = vr[1];
    };

    loadKV(0);
    writeKV();
    __syncthreads();

    for (int t = 0; t < n_mt; ++t) {
        if (t + 1 < n_mt) loadKV(t + 1);    // issue early (hidden under compute)

        // ---- S = Q K^T ----
        f32x4 accS[4] = {};
#pragma unroll
        for (int ks = 0; ks < 2; ++ks) {
            const int g = ks * 4 + lg;
            const int ra_ = wq + li;
            bf16x8 a = *(const bf16x8*)&Qs[ra_ * 64 + ((g ^ (ra_ & 7)) * 8)];
#pragma unroll
            for (int j = 0; j < 4; ++j) {
                const int rb_ = j * 16 + li;
                bf16x8 b = *(const bf16x8*)&Ks[rb_ * 64 + ((g ^ (rb_ & 7)) * 8)];
                accS[j] = __builtin_amdgcn_mfma_f32_16x16x32_bf16(a, b, accS[j], 0, 0, 0);
            }
        }

        // ---- P = exp(S/8) masked; write Ps ----
        const int m0 = t * 64;
#pragma unroll
        for (int rg = 0; rg < 4; ++rg) {
            const int qrow = q0 + wq + lg * 4 + rg;
#pragma unroll
            for (int j = 0; j < 4; ++j) {
                int mcol = m0 + j * 16 + li;
                float p = (mcol > qrow || mcol >= L) ? 0.f : __expf(accS[j][rg] * 0.125f);
                Ps[wq + lg * 4 + rg][j * 16 + li] = f2b(p);
            }
        }

        // ---- O += P V ; L += P 1 ----
#pragma unroll
        for (int ks = 0; ks < 2; ++ks) {
            bf16x8 a = *(const bf16x8*)&Ps[wq + li][ks * 32 + lg * 8];
            accL = __builtin_amdgcn_mfma_f32_16x16x32_bf16(a, ones, accL, 0, 0, 0);
#pragma unroll
            for (int j = 0; j < 4; ++j) {
                const int g = ks * 4 + lg;
                const int rb_ = j * 16 + li;
                bf16x8 b = *(const bf16x8*)&Vs[rb_ * 64 + ((g ^ (rb_ & 7)) * 8)];
                accO[j] = __builtin_amdgcn_mfma_f32_16x16x32_bf16(a, b, accO[j], 0, 0, 0);
            }
        }
        __syncthreads();                    // done reading Ks/Vs
        if (t + 1 < n_mt) {
            writeKV();                      // vmcnt wait lands here
            __syncthreads();
        }
    }

    // ---- epilogue: h += O / L ----
    const int b_ = bh / H, hh = bh % H;
#pragma unroll
    for (int rg = 0; rg < 4; ++rg) {
        const int qrow = q0 + wq + lg * 4 + rg;
        if (qrow >= L) continue;
        const float inv = 1.f / accL[rg];
        float* dst = hbuf + ((size_t)b_ * L + qrow) * D + hh * HS;
#pragma unroll
        for (int j = 0; j < 4; ++j)
            dst[j * 16 + li] += accO[j][rg] * inv;
    }
}

// ---------------------------------------------------------------------------
extern "C" void kernel_launch(void* const* d_in, const int* in_sizes, int n_in,
                              void* d_out, int out_size, void* d_ws, size_t ws_size,
                              hipStream_t stream)
{
    const int*   x    = (const int*)d_in[0];
    const float* emb  = (const float*)d_in[1];
    const float* pos  = (const float*)d_in[2];
    const float* Wq   = (const float*)d_in[3];
    const float* Wk   = (const float*)d_in[4];
    const float* Wv   = (const float*)d_in[5];
    const float* ln1g = (const float*)d_in[6];
    const float* ln1b = (const float*)d_in[7];
    const float* ln2g = (const float*)d_in[8];
    const float* ln2b = (const float*)d_in[9];
    const float* mlpW = (const float*)d_in[10];
    const float* mlpb = (const float*)d_in[11];
    const float* fcW  = (const float*)d_in[12];
    const float* fcb  = (const float*)d_in[13];
    float* out = (float*)d_out;

    // workspace layout — all 16B aligned
    char* ws = (char*)d_ws;
    float*  h   = (float*)ws;    ws += (size_t)BL * D * 4;
    float*  h2  = (float*)ws;    ws += (size_t)BL * D * 4;
    ushort* qb  = (ushort*)ws;   ws += (size_t)BL * D * 2;
    ushort* kbuf= (ushort*)ws;   ws += (size_t)BL * D * 2;
    ushort* vT  = (ushort*)ws;   ws += (size_t)B * H * HS * LP * 2;
    ushort* hb  = (ushort*)ws;   ws += (size_t)BL * D * 2;
    ushort* Wp  = (ushort*)ws;   ws += (size_t)NL * 1536 * 512 * 2;
    ushort* Wtm = (ushort*)ws;   ws += (size_t)NL * D * D * 2;
    ushort* Wtf = (ushort*)ws;   ws += (size_t)576 * 512 * 2;
    float* s1q  = (float*)ws;    ws += (size_t)NL * 1536 * 4;
    float* s2q  = (float*)ws;    ws += (size_t)NL * 1536 * 4;
    float* s1m  = (float*)ws;    ws += (size_t)NL * 512 * 4;
    float* s2m  = (float*)ws;    ws += (size_t)NL * 512 * 4;

    cvt_qkv_k<<<dim3(NL * H, 3), 256, 0, stream>>>(Wq, Wk, Wv, ln1g, ln1b, Wp, s1q, s2q);
    cvt_mlp_k<<<dim3(8, NL), 256, 0, stream>>>(mlpW, ln2g, ln2b, Wtm, s1m, s2m);
    cvt_fc_k<<<dim3(9, 8), 256, 0, stream>>>(fcW, Wtf);

    embed4_k<<<BL / 4, 256, 0, stream>>>(x, emb, pos, h);

    float* hc = h;
    float* hn = h2;
    for (int i = 0; i < NL; ++i) {
        mgemm_k<0><<<dim3(24, 65), 256, 0, stream>>>(
            hc, Wp + (size_t)i * 1536 * 512, s1q + (size_t)i * 1536, s2q + (size_t)i * 1536,
            nullptr, qb, kbuf, vT);
        fattn_k<<<B * H * 9, 256, 0, stream>>>(qb, kbuf, vT, hc);
        if (i < NL - 1) {
            mgemm_k<1><<<dim3(8, 65), 256, 0, stream>>>(
                hc, Wtm + (size_t)i * D * D, s1m + (size_t)i * 512, s2m + (size_t)i * 512,
                mlpb + i * D, hn, hc, nullptr);
            float* t = hc; hc = hn; hn = t;
        } else {
            mgemm_k<3><<<dim3(8, 65), 256, 0, stream>>>(
                hc, Wtm + (size_t)i * D * D, s1m + (size_t)i * 512, s2m + (size_t)i * 512,
                mlpb + i * D, hb, hc, nullptr);
        }
    }
    mgemm_k<2><<<dim3(9, 65), 256, 0, stream>>>(hb, Wtf, nullptr, nullptr, fcb,
                                                out, nullptr, nullptr);
}

// Round 13
// 544.492 us; speedup vs baseline: 1.3949x; 1.3949x over previous
//
#include <hip/hip_runtime.h>
#include <hip/hip_bf16.h>
#include <math.h>

#define B 8
#define L 513
#define D 512
#define H 8
#define HS 64
#define V 513
#define NL 6
#define BL (B * L)          // 4104
#define LP 576              // padded L for vT
#define EPS 1e-5f

typedef __attribute__((ext_vector_type(8))) short bf16x8;   // 8 bf16 (4 VGPRs)
typedef __attribute__((ext_vector_type(4))) float f32x4;    // MFMA accumulator

__device__ inline ushort f2b(float f) {
    __hip_bfloat16 h = __float2bfloat16(f);
    return *reinterpret_cast<ushort*>(&h);
}

// ---------------------------------------------------------------------------
// LayerNorm core: one wave handles one row (8 elems/lane, shuffle reduce).
// ---------------------------------------------------------------------------
__device__ inline void ln_row(float4 v0, float4 v1, const float* g,
                              const float* b, int lane, ushort* orow)
{
    float s = v0.x + v0.y + v0.z + v0.w + v1.x + v1.y + v1.z + v1.w;
#pragma unroll
    for (int off = 1; off < 64; off <<= 1) s += __shfl_xor(s, off);
    const float mu = s * (1.f / D);
    float d0 = v0.x - mu, d1 = v0.y - mu, d2 = v0.z - mu, d3 = v0.w - mu;
    float d4 = v1.x - mu, d5 = v1.y - mu, d6 = v1.z - mu, d7 = v1.w - mu;
    float ss = d0*d0 + d1*d1 + d2*d2 + d3*d3 + d4*d4 + d5*d5 + d6*d6 + d7*d7;
#pragma unroll
    for (int off = 1; off < 64; off <<= 1) ss += __shfl_xor(ss, off);
    const float rs = rsqrtf(ss * (1.f / D) + EPS);
    const float* gp = g + lane * 8;
    const float* bp = b + lane * 8;
    float4 g0 = *(const float4*)gp, g1 = *(const float4*)(gp + 4);
    float4 b0 = *(const float4*)bp, b1 = *(const float4*)(bp + 4);
    ushort4 u0, u1;
    u0.x = f2b(d0 * rs * g0.x + b0.x); u0.y = f2b(d1 * rs * g0.y + b0.y);
    u0.z = f2b(d2 * rs * g0.z + b0.z); u0.w = f2b(d3 * rs * g0.w + b0.w);
    u1.x = f2b(d4 * rs * g1.x + b1.x); u1.y = f2b(d5 * rs * g1.y + b1.y);
    u1.z = f2b(d6 * rs * g1.z + b1.z); u1.w = f2b(d7 * rs * g1.w + b1.w);
    *(ushort4*)orow       = u0;
    *(ushort4*)(orow + 4) = u1;
}

// LN: 4 rows per block (4 waves), BL = 4 * 1026
__global__ __launch_bounds__(256) void ln4_k(const float* __restrict__ x,
                                             const float* __restrict__ g,
                                             const float* __restrict__ b,
                                             ushort* __restrict__ o)
{
    const int wave = threadIdx.x >> 6, lane = threadIdx.x & 63;
    const int row = blockIdx.x * 4 + wave;
    const float* xr = x + (size_t)row * D + lane * 8;
    float4 v0 = *(const float4*)xr;
    float4 v1 = *(const float4*)(xr + 4);
    ln_row(v0, v1, g, b, lane, o + (size_t)row * D + lane * 8);
}

// Layer-0 LN fused with embedding: h = emb[x]+pos written, then LN -> o.
__global__ __launch_bounds__(256) void ln_embed4_k(const int* __restrict__ xi,
                                                   const float* __restrict__ emb,
                                                   const float* __restrict__ pos,
                                                   const float* __restrict__ g,
                                                   const float* __restrict__ b,
                                                   float* __restrict__ h,
                                                   ushort* __restrict__ o)
{
    const int wave = threadIdx.x >> 6, lane = threadIdx.x & 63;
    const int row = blockIdx.x * 4 + wave;
    const int l = row % L;
    const int tok = xi[row];
    const float* er = emb + (size_t)tok * D + lane * 8;
    const float* pr = pos + (size_t)l * D + lane * 8;
    float4 e0 = *(const float4*)er, e1 = *(const float4*)(er + 4);
    float4 p0 = *(const float4*)pr, p1 = *(const float4*)(pr + 4);
    float4 v0 = make_float4(e0.x + p0.x, e0.y + p0.y, e0.z + p0.z, e0.w + p0.w);
    float4 v1 = make_float4(e1.x + p1.x, e1.y + p1.y, e1.z + p1.z, e1.w + p1.w);
    float* hr = h + (size_t)row * D + lane * 8;
    *(float4*)hr       = v0;
    *(float4*)(hr + 4) = v1;
    ln_row(v0, v1, g, b, lane, o + (size_t)row * D + lane * 8);
}

// ---------------------------------------------------------------------------
// Weight pack/cast kernels.
// QKV: W[sel][i][h][d][e] -> Wp[i][n][d] bf16, n = sel*512 + h*64 + e
// ---------------------------------------------------------------------------
__global__ __launch_bounds__(256) void cvt_qkv_k(const float* __restrict__ Wq,
                                                 const float* __restrict__ Wk,
                                                 const float* __restrict__ Wv,
                                                 ushort* __restrict__ Wp)
{
    const int dc = blockIdx.x;
    const int i  = blockIdx.y / H, h = blockIdx.y % H;
    const int sel = blockIdx.z;
    const float* W = (sel == 0) ? Wq : (sel == 1) ? Wk : Wv;
    const float* src = W + ((size_t)i * H + h) * D * HS + (size_t)dc * 64 * HS;
    __shared__ float T[64][65];
    const int tid = threadIdx.x;
#pragma unroll
    for (int it = 0; it < 4; ++it) {
        int idx = tid + it * 256;
        int r = idx >> 4, e4 = (idx & 15) * 4;
        float4 f = *(const float4*)(src + (size_t)r * HS + e4);
        T[r][e4] = f.x; T[r][e4 + 1] = f.y; T[r][e4 + 2] = f.z; T[r][e4 + 3] = f.w;
    }
    __syncthreads();
    ushort* dst = Wp + (size_t)i * 1536 * 512 + (size_t)(sel * 512 + h * 64) * 512 + dc * 64;
#pragma unroll
    for (int it = 0; it < 4; ++it) {
        int idx = tid + it * 256;
        int e = idx >> 4, d4 = (idx & 15) * 4;
        ushort4 u;
        u.x = f2b(T[d4][e]); u.y = f2b(T[d4 + 1][e]);
        u.z = f2b(T[d4 + 2][e]); u.w = f2b(T[d4 + 3][e]);
        *(ushort4*)(dst + (size_t)e * 512 + d4) = u;
    }
}

// mlp_W[i][k][n] (D,D) -> Wt[i][n][k] bf16
__global__ __launch_bounds__(256) void cvt_mlp_k(const float* __restrict__ Wm,
                                                 ushort* __restrict__ Wt)
{
    const int nt = blockIdx.x, kt = blockIdx.y, i = blockIdx.z;
    const float* src = Wm + (size_t)i * D * D;
    __shared__ float T[64][65];
    const int tid = threadIdx.x;
#pragma unroll
    for (int it = 0; it < 4; ++it) {
        int idx = tid + it * 256;
        int r = idx >> 4, e4 = (idx & 15) * 4;
        float4 f = *(const float4*)(src + (size_t)(kt * 64 + r) * D + nt * 64 + e4);
        T[r][e4] = f.x; T[r][e4 + 1] = f.y; T[r][e4 + 2] = f.z; T[r][e4 + 3] = f.w;
    }
    __syncthreads();
    ushort* dst = Wt + (size_t)i * D * D + (size_t)(nt * 64) * D + kt * 64;
#pragma unroll
    for (int it = 0; it < 4; ++it) {
        int idx = tid + it * 256;
        int e = idx >> 4, k4 = (idx & 15) * 4;
        ushort4 u;
        u.x = f2b(T[k4][e]); u.y = f2b(T[k4 + 1][e]);
        u.z = f2b(T[k4 + 2][e]); u.w = f2b(T[k4 + 3][e]);
        *(ushort4*)(dst + (size_t)e * D + k4) = u;
    }
}

// fc_W[k][n] (512,513) -> Wt[n][k] bf16, n padded to 576 with zeros
__global__ __launch_bounds__(256) void cvt_fc_k(const float* __restrict__ Wf,
                                                ushort* __restrict__ Wt)
{
    const int nt = blockIdx.x, kt = blockIdx.y;     // 9 x 8
    __shared__ float T[64][65];
    const int tid = threadIdx.x;
#pragma unroll
    for (int it = 0; it < 4; ++it) {
        int idx = tid + it * 256;
        int r = idx >> 4, e4 = (idx & 15) * 4;
#pragma unroll
        for (int j = 0; j < 4; ++j) {
            int n = nt * 64 + e4 + j;
            T[r][e4 + j] = (n < V) ? Wf[(size_t)(kt * 64 + r) * V + n] : 0.f;
        }
    }
    __syncthreads();
    ushort* dst = Wt + (size_t)(nt * 64) * 512 + kt * 64;
#pragma unroll
    for (int it = 0; it < 4; ++it) {
        int idx = tid + it * 256;
        int e = idx >> 4, k4 = (idx & 15) * 4;
        ushort4 u;
        u.x = f2b(T[k4][e]); u.y = f2b(T[k4 + 1][e]);
        u.z = f2b(T[k4 + 2][e]); u.w = f2b(T[k4 + 3][e]);
        *(ushort4*)(dst + (size_t)e * 512 + k4) = u;
    }
}

// ---------------------------------------------------------------------------
// bf16 MFMA GEMM (R8 loop structure: single buffer, 2 barriers/K-step) with
// XOR bank swizzle on linear [64x64] LDS (write slot kc^(r&7), read slot
// g^(row&7)) -> conflict-free staging writes AND ds_read_b128. 16 KB LDS.
// MODE 0: QKV (N=1536): q/k bf16 (B,H,L,HS); v bf16 transposed (B,H,HS,LP).
// MODE 1: MLP (N=512):  o0 fp32 = gelu(acc+bias) + o0 (in-place h).
// MODE 2: FC  (N=576p): o0 fp32 [r*V+c] = acc + bias[c], c < V.
// MODE 3: MLP final:    o0 bf16 = f2b(gelu(acc+bias) + o1[r*D+c]).
// ---------------------------------------------------------------------------
template <int MODE>
__global__ __launch_bounds__(256) void mgemm_k(const ushort* __restrict__ A,
                                               const ushort* __restrict__ Bt,
                                               const float* __restrict__ bias,
                                               void* __restrict__ o0,
                                               void* __restrict__ o1,
                                               void* __restrict__ o2)
{
    __shared__ ushort As[64 * 64];
    __shared__ ushort Bs[64 * 64];
    const int tid  = threadIdx.x;
    const int wave = tid >> 6, lane = tid & 63;
    const int row0 = blockIdx.y * 64;
    const int col0 = blockIdx.x * 64;
    const int wr = (wave >> 1) * 32, wc = (wave & 1) * 32;
    const int frow = lane & 15;
    const int kb   = lane >> 4;

    const int sr0 = tid >> 3, skc = tid & 7;
    const int sr1 = (tid + 256) >> 3;
    const int ss0 = (skc ^ (sr0 & 7)) * 8;
    const int ss1 = (skc ^ (sr1 & 7)) * 8;

    f32x4 acc[2][2] = {};

    for (int k0 = 0; k0 < 512; k0 += 64) {
        {
            uint4 av = make_uint4(0u, 0u, 0u, 0u);
            if (row0 + sr0 < BL)
                av = *(const uint4*)(A + (size_t)(row0 + sr0) * 512 + k0 + skc * 8);
            *(uint4*)&As[sr0 * 64 + ss0] = av;
            uint4 bv = *(const uint4*)(Bt + (size_t)(col0 + sr0) * 512 + k0 + skc * 8);
            *(uint4*)&Bs[sr0 * 64 + ss0] = bv;
            av = make_uint4(0u, 0u, 0u, 0u);
            if (row0 + sr1 < BL)
                av = *(const uint4*)(A + (size_t)(row0 + sr1) * 512 + k0 + skc * 8);
            *(uint4*)&As[sr1 * 64 + ss1] = av;
            bv = *(const uint4*)(Bt + (size_t)(col0 + sr1) * 512 + k0 + skc * 8);
            *(uint4*)&Bs[sr1 * 64 + ss1] = bv;
        }
        __syncthreads();
#pragma unroll
        for (int ks = 0; ks < 2; ++ks) {
            bf16x8 a[2], b[2];
            const int g = ks * 4 + kb;
#pragma unroll
            for (int f = 0; f < 2; ++f) {
                const int ra_ = wr + f * 16 + frow;
                a[f] = *(const bf16x8*)&As[ra_ * 64 + ((g ^ (ra_ & 7)) * 8)];
                const int rb_ = wc + f * 16 + frow;
                b[f] = *(const bf16x8*)&Bs[rb_ * 64 + ((g ^ (rb_ & 7)) * 8)];
            }
#pragma unroll
            for (int fi = 0; fi < 2; ++fi)
#pragma unroll
                for (int fj = 0; fj < 2; ++fj)
                    acc[fi][fj] = __builtin_amdgcn_mfma_f32_16x16x32_bf16(
                        a[fi], b[fj], acc[fi][fj], 0, 0, 0);
        }
        __syncthreads();
    }

    // C frag layout: col = lane&15, row = (lane>>4)*4 + reg
    const int rbase = row0 + wr + (lane >> 4) * 4;
    const int cbase = col0 + wc + (lane & 15);
#pragma unroll
    for (int fi = 0; fi < 2; ++fi) {
#pragma unroll
        for (int fj = 0; fj < 2; ++fj) {
            const int c = cbase + fj * 16;
#pragma unroll
            for (int rg = 0; rg < 4; ++rg) {
                const int r = rbase + fi * 16 + rg;
                if (r >= BL) continue;
                float val = acc[fi][fj][rg];
                if (MODE == 0) {
                    int buf = c >> 9, cc = c & 511;
                    int b_ = r / L, l = r % L;
                    int head = cc >> 6, e = cc & 63;
                    int bh = b_ * H + head;
                    if (buf == 0)
                        ((ushort*)o0)[((size_t)bh * L + l) * HS + e] = f2b(val);
                    else if (buf == 1)
                        ((ushort*)o1)[((size_t)bh * L + l) * HS + e] = f2b(val);
                    else
                        ((ushort*)o2)[((size_t)bh * HS + e) * LP + l] = f2b(val);
                } else if (MODE == 1) {
                    float xv = val + bias[c];
                    float gl = 0.5f * xv * (1.f + erff(xv * 0.70710678118654752f));
                    ((float*)o0)[(size_t)r * D + c] = gl + ((float*)o0)[(size_t)r * D + c];
                } else if (MODE == 3) {
                    float xv = val + bias[c];
                    float gl = 0.5f * xv * (1.f + erff(xv * 0.70710678118654752f));
                    float res = ((const float*)o1)[(size_t)r * D + c];
                    ((ushort*)o0)[(size_t)r * D + c] = f2b(gl + res);
                } else {
                    if (c < V) ((float*)o0)[(size_t)r * V + c] = val + bias[c];
                }
            }
        }
    }
}

// ---------------------------------------------------------------------------
// MFMA flash attention (R8 structure: single-buffered K/V with register
// prefetch, 2 barriers/tile) + XOR swizzle on Qs/Ks/Vs (linear 64x64).
// Fixed-max softmax (scores bounded) + ones-column MFMA row-sum. 33 KB LDS.
// ---------------------------------------------------------------------------
__global__ __launch_bounds__(256) void fattn_k(const ushort* __restrict__ qb,
                                               const ushort* __restrict__ kb,
                                               const ushort* __restrict__ vT,
                                               float* __restrict__ hbuf)
{
    __shared__ ushort Qs[64 * 64];
    __shared__ ushort Ks[64 * 64];
    __shared__ ushort Vs[64 * 64];   // [e][kv]
    __shared__ ushort Ps[64][72];

    const int bx  = blockIdx.x;
    const int bh  = bx / 9;
    const int qt  = 8 - (bx % 9);        // big tiles dispatched first
    const int q0  = qt * 64;
    const int tid = threadIdx.x;
    const int wave = tid >> 6, lane = tid & 63;
    const int lg = lane >> 4, li = lane & 15;
    const int wq = wave * 16;

    const int sr0 = tid >> 3, skc = tid & 7;
    const int sr1 = (tid + 256) >> 3;
    const int ss0 = (skc ^ (sr0 & 7)) * 8;
    const int ss1 = (skc ^ (sr1 & 7)) * 8;

    // ---- stage Q (swizzled) ----
    {
        int qr = q0 + sr0;
        uint4 v = make_uint4(0u, 0u, 0u, 0u);
        if (qr < L) v = *(const uint4*)(qb + ((size_t)bh * L + qr) * HS + skc * 8);
        *(uint4*)&Qs[sr0 * 64 + ss0] = v;
        qr = q0 + sr1;
        v = make_uint4(0u, 0u, 0u, 0u);
        if (qr < L) v = *(const uint4*)(qb + ((size_t)bh * L + qr) * HS + skc * 8);
        *(uint4*)&Qs[sr1 * 64 + ss1] = v;
    }

    const short one_b = (short)0x3F80;                 // bf16 1.0
    const bf16x8 ones = { one_b, one_b, one_b, one_b, one_b, one_b, one_b, one_b };

    f32x4 accO[4] = {};
    f32x4 accL = {};

    const int n_mt = qt + 1;
    uint4 kr[2], vr[2];

    auto loadKV = [&](int t) {
        int mr = t * 64 + sr0;
        kr[0] = make_uint4(0u, 0u, 0u, 0u);
        if (mr < L) kr[0] = *(const uint4*)(kb + ((size_t)bh * L + mr) * HS + skc * 8);
        vr[0] = *(const uint4*)(vT + ((size_t)bh * HS + sr0) * LP + t * 64 + skc * 8);
        mr = t * 64 + sr1;
        kr[1] = make_uint4(0u, 0u, 0u, 0u);
        if (mr < L) kr[1] = *(const uint4*)(kb + ((size_t)bh * L + mr) * HS + skc * 8);
        vr[1] = *(const uint4*)(vT + ((size_t)bh * HS + sr1) * LP + t * 64 + skc * 8);
    };
    auto writeKV = [&]() {
        *(uint4*)&Ks[sr0 * 64 + ss0] = kr[0];
        *(uint4*)&Vs[sr0 * 64 + ss0] = vr[0];
        *(uint4*)&Ks[sr1 * 64 + ss1] = kr[1];
        *(uint4*)&Vs[sr1 * 64 + ss1] = vr[1];
    };

    loadKV(0);
    writeKV();
    __syncthreads();

    for (int t = 0; t < n_mt; ++t) {
        if (t + 1 < n_mt) loadKV(t + 1);    // issue early (hidden under compute)

        // ---- S = Q K^T ----
        f32x4 accS[4] = {};
#pragma unroll
        for (int ks = 0; ks < 2; ++ks) {
            const int g = ks * 4 + lg;
            const int ra_ = wq + li;
            bf16x8 a = *(const bf16x8*)&Qs[ra_ * 64 + ((g ^ (ra_ & 7)) * 8)];
#pragma unroll
            for (int j = 0; j < 4; ++j) {
                const int rb_ = j * 16 + li;
                bf16x8 b = *(const bf16x8*)&Ks[rb_ * 64 + ((g ^ (rb_ & 7)) * 8)];
                accS[j] = __builtin_amdgcn_mfma_f32_16x16x32_bf16(a, b, accS[j], 0, 0, 0);
            }
        }

        // ---- P = exp(S/8) masked; write Ps ----
        const int m0 = t * 64;
#pragma unroll
        for (int rg = 0; rg < 4; ++rg) {
            const int qrow = q0 + wq + lg * 4 + rg;
#pragma unroll
            for (int j = 0; j < 4; ++j) {
                int mcol = m0 + j * 16 + li;
                float p = (mcol > qrow || mcol >= L) ? 0.f : __expf(accS[j][rg] * 0.125f);
                Ps[wq + lg * 4 + rg][j * 16 + li] = f2b(p);
            }
        }

        // ---- O += P V ; L += P 1 ----
#pragma unroll
        for (int ks = 0; ks < 2; ++ks) {
            bf16x8 a = *(const bf16x8*)&Ps[wq + li][ks * 32 + lg * 8];
            accL = __builtin_amdgcn_mfma_f32_16x16x32_bf16(a, ones, accL, 0, 0, 0);
#pragma unroll
            for (int j = 0; j < 4; ++j) {
                const int g = ks * 4 + lg;
                const int rb_ = j * 16 + li;
                bf16x8 b = *(const bf16x8*)&Vs[rb_ * 64 + ((g ^ (rb_ & 7)) * 8)];
                accO[j] = __builtin_amdgcn_mfma_f32_16x16x32_bf16(a, b, accO[j], 0, 0, 0);
            }
        }
        __syncthreads();                    // done reading Ks/Vs
        if (t + 1 < n_mt) {
            writeKV();                      // vmcnt wait lands here
            __syncthreads();
        }
    }

    // ---- epilogue: h += O / L ----
    const int b_ = bh / H, hh = bh % H;
#pragma unroll
    for (int rg = 0; rg < 4; ++rg) {
        const int qrow = q0 + wq + lg * 4 + rg;
        if (qrow >= L) continue;
        const float inv = 1.f / accL[rg];
        float* dst = hbuf + ((size_t)b_ * L + qrow) * D + hh * HS;
#pragma unroll
        for (int j = 0; j < 4; ++j)
            dst[j * 16 + li] += accO[j][rg] * inv;
    }
}

// ---------------------------------------------------------------------------
extern "C" void kernel_launch(void* const* d_in, const int* in_sizes, int n_in,
                              void* d_out, int out_size, void* d_ws, size_t ws_size,
                              hipStream_t stream)
{
    const int*   x    = (const int*)d_in[0];
    const float* emb  = (const float*)d_in[1];
    const float* pos  = (const float*)d_in[2];
    const float* Wq   = (const float*)d_in[3];
    const float* Wk   = (const float*)d_in[4];
    const float* Wv   = (const float*)d_in[5];
    const float* ln1g = (const float*)d_in[6];
    const float* ln1b = (const float*)d_in[7];
    const float* ln2g = (const float*)d_in[8];
    const float* ln2b = (const float*)d_in[9];
    const float* mlpW = (const float*)d_in[10];
    const float* mlpb = (const float*)d_in[11];
    const float* fcW  = (const float*)d_in[12];
    const float* fcb  = (const float*)d_in[13];
    float* out = (float*)d_out;

    // workspace layout — all 16B aligned
    char* ws = (char*)d_ws;
    float*  h   = (float*)ws;    ws += (size_t)BL * D * 4;
    ushort* qb  = (ushort*)ws;   ws += (size_t)BL * D * 2;
    ushort* kbuf= (ushort*)ws;   ws += (size_t)BL * D * 2;
    ushort* vT  = (ushort*)ws;   ws += (size_t)B * H * HS * LP * 2;
    ushort* xnb = (ushort*)ws;   ws += (size_t)BL * D * 2;
    ushort* hb  = (ushort*)ws;   ws += (size_t)BL * D * 2;
    ushort* Wp  = (ushort*)ws;   ws += (size_t)NL * 1536 * 512 * 2;
    ushort* Wtm = (ushort*)ws;   ws += (size_t)NL * D * D * 2;
    ushort* Wtf = (ushort*)ws;   ws += (size_t)576 * 512 * 2;

    cvt_qkv_k<<<dim3(8, NL * H, 3), 256, 0, stream>>>(Wq, Wk, Wv, Wp);
    cvt_mlp_k<<<dim3(8, 8, NL), 256, 0, stream>>>(mlpW, Wtm);
    cvt_fc_k<<<dim3(9, 8), 256, 0, stream>>>(fcW, Wtf);

    for (int i = 0; i < NL; ++i) {
        if (i == 0)
            ln_embed4_k<<<BL / 4, 256, 0, stream>>>(x, emb, pos, ln1g, ln1b, h, xnb);
        else
            ln4_k<<<BL / 4, 256, 0, stream>>>(h, ln1g + i * D, ln1b + i * D, xnb);
        mgemm_k<0><<<dim3(24, 65), 256, 0, stream>>>(
            xnb, Wp + (size_t)i * 1536 * 512, nullptr, qb, kbuf, vT);
        fattn_k<<<B * H * 9, 256, 0, stream>>>(qb, kbuf, vT, h);
        ln4_k<<<BL / 4, 256, 0, stream>>>(h, ln2g + i * D, ln2b + i * D, xnb);
        if (i < NL - 1)
            mgemm_k<1><<<dim3(8, 65), 256, 0, stream>>>(
                xnb, Wtm + (size_t)i * D * D, mlpb + i * D, h, nullptr, nullptr);
        else
            mgemm_k<3><<<dim3(8, 65), 256, 0, stream>>>(
                xnb, Wtm + (size_t)i * D * D, mlpb + i * D, hb, h, nullptr);
    }
    mgemm_k<2><<<dim3(9, 65), 256, 0, stream>>>(hb, Wtf, fcb, out, nullptr, nullptr);
}

// Round 14
// 535.206 us; speedup vs baseline: 1.4191x; 1.0174x over previous
//
#include <hip/hip_runtime.h>
#include <hip/hip_bf16.h>
#include <math.h>

#define B 8
#define L 513
#define D 512
#define H 8
#define HS 64
#define V 513
#define NL 6
#define BL (B * L)          // 4104
#define LP 576              // padded L for vT
#define EPS 1e-5f

typedef __attribute__((ext_vector_type(8))) short bf16x8;   // 8 bf16 (4 VGPRs)
typedef __attribute__((ext_vector_type(4))) float f32x4;    // MFMA accumulator

__device__ inline ushort f2b(float f) {
    __hip_bfloat16 h = __float2bfloat16(f);
    return *reinterpret_cast<ushort*>(&h);
}

// async global->LDS, 16B/lane; LDS dest = wave-uniform base + lane*16.
__device__ inline void gload16(const void* g, void* l) {
    __builtin_amdgcn_global_load_lds(
        (const __attribute__((address_space(1))) void*)g,
        (__attribute__((address_space(3))) void*)l, 16, 0, 0);
}

// ---------------------------------------------------------------------------
// LayerNorm core: one wave handles one row (8 elems/lane, shuffle reduce).
// ---------------------------------------------------------------------------
__device__ inline void ln_row(float4 v0, float4 v1, const float* g,
                              const float* b, int lane, ushort* orow)
{
    float s = v0.x + v0.y + v0.z + v0.w + v1.x + v1.y + v1.z + v1.w;
#pragma unroll
    for (int off = 1; off < 64; off <<= 1) s += __shfl_xor(s, off);
    const float mu = s * (1.f / D);
    float d0 = v0.x - mu, d1 = v0.y - mu, d2 = v0.z - mu, d3 = v0.w - mu;
    float d4 = v1.x - mu, d5 = v1.y - mu, d6 = v1.z - mu, d7 = v1.w - mu;
    float ss = d0*d0 + d1*d1 + d2*d2 + d3*d3 + d4*d4 + d5*d5 + d6*d6 + d7*d7;
#pragma unroll
    for (int off = 1; off < 64; off <<= 1) ss += __shfl_xor(ss, off);
    const float rs = rsqrtf(ss * (1.f / D) + EPS);
    const float* gp = g + lane * 8;
    const float* bp = b + lane * 8;
    float4 g0 = *(const float4*)gp, g1 = *(const float4*)(gp + 4);
    float4 b0 = *(const float4*)bp, b1 = *(const float4*)(bp + 4);
    ushort4 u0, u1;
    u0.x = f2b(d0 * rs * g0.x + b0.x); u0.y = f2b(d1 * rs * g0.y + b0.y);
    u0.z = f2b(d2 * rs * g0.z + b0.z); u0.w = f2b(d3 * rs * g0.w + b0.w);
    u1.x = f2b(d4 * rs * g1.x + b1.x); u1.y = f2b(d5 * rs * g1.y + b1.y);
    u1.z = f2b(d6 * rs * g1.z + b1.z); u1.w = f2b(d7 * rs * g1.w + b1.w);
    *(ushort4*)orow       = u0;
    *(ushort4*)(orow + 4) = u1;
}

// LN: 4 rows per block (4 waves), BL = 4 * 1026
__global__ __launch_bounds__(256) void ln4_k(const float* __restrict__ x,
                                             const float* __restrict__ g,
                                             const float* __restrict__ b,
                                             ushort* __restrict__ o)
{
    const int wave = threadIdx.x >> 6, lane = threadIdx.x & 63;
    const int row = blockIdx.x * 4 + wave;
    const float* xr = x + (size_t)row * D + lane * 8;
    float4 v0 = *(const float4*)xr;
    float4 v1 = *(const float4*)(xr + 4);
    ln_row(v0, v1, g, b, lane, o + (size_t)row * D + lane * 8);
}

// Layer-0 LN fused with embedding: h = emb[x]+pos written, then LN -> o.
__global__ __launch_bounds__(256) void ln_embed4_k(const int* __restrict__ xi,
                                                   const float* __restrict__ emb,
                                                   const float* __restrict__ pos,
                                                   const float* __restrict__ g,
                                                   const float* __restrict__ b,
                                                   float* __restrict__ h,
                                                   ushort* __restrict__ o)
{
    const int wave = threadIdx.x >> 6, lane = threadIdx.x & 63;
    const int row = blockIdx.x * 4 + wave;
    const int l = row % L;
    const int tok = xi[row];
    const float* er = emb + (size_t)tok * D + lane * 8;
    const float* pr = pos + (size_t)l * D + lane * 8;
    float4 e0 = *(const float4*)er, e1 = *(const float4*)(er + 4);
    float4 p0 = *(const float4*)pr, p1 = *(const float4*)(pr + 4);
    float4 v0 = make_float4(e0.x + p0.x, e0.y + p0.y, e0.z + p0.z, e0.w + p0.w);
    float4 v1 = make_float4(e1.x + p1.x, e1.y + p1.y, e1.z + p1.z, e1.w + p1.w);
    float* hr = h + (size_t)row * D + lane * 8;
    *(float4*)hr       = v0;
    *(float4*)(hr + 4) = v1;
    ln_row(v0, v1, g, b, lane, o + (size_t)row * D + lane * 8);
}

// ---------------------------------------------------------------------------
// Weight pack/cast kernels.
// QKV: W[sel][i][h][d][e] -> Wp[i][n][d] bf16, n = sel*512 + h*64 + e
// ---------------------------------------------------------------------------
__global__ __launch_bounds__(256) void cvt_qkv_k(const float* __restrict__ Wq,
                                                 const float* __restrict__ Wk,
                                                 const float* __restrict__ Wv,
                                                 ushort* __restrict__ Wp)
{
    const int dc = blockIdx.x;
    const int i  = blockIdx.y / H, h = blockIdx.y % H;
    const int sel = blockIdx.z;
    const float* W = (sel == 0) ? Wq : (sel == 1) ? Wk : Wv;
    const float* src = W + ((size_t)i * H + h) * D * HS + (size_t)dc * 64 * HS;
    __shared__ float T[64][65];
    const int tid = threadIdx.x;
#pragma unroll
    for (int it = 0; it < 4; ++it) {
        int idx = tid + it * 256;
        int r = idx >> 4, e4 = (idx & 15) * 4;
        float4 f = *(const float4*)(src + (size_t)r * HS + e4);
        T[r][e4] = f.x; T[r][e4 + 1] = f.y; T[r][e4 + 2] = f.z; T[r][e4 + 3] = f.w;
    }
    __syncthreads();
    ushort* dst = Wp + (size_t)i * 1536 * 512 + (size_t)(sel * 512 + h * 64) * 512 + dc * 64;
#pragma unroll
    for (int it = 0; it < 4; ++it) {
        int idx = tid + it * 256;
        int e = idx >> 4, d4 = (idx & 15) * 4;
        ushort4 u;
        u.x = f2b(T[d4][e]); u.y = f2b(T[d4 + 1][e]);
        u.z = f2b(T[d4 + 2][e]); u.w = f2b(T[d4 + 3][e]);
        *(ushort4*)(dst + (size_t)e * 512 + d4) = u;
    }
}

// mlp_W[i][k][n] (D,D) -> Wt[i][n][k] bf16
__global__ __launch_bounds__(256) void cvt_mlp_k(const float* __restrict__ Wm,
                                                 ushort* __restrict__ Wt)
{
    const int nt = blockIdx.x, kt = blockIdx.y, i = blockIdx.z;
    const float* src = Wm + (size_t)i * D * D;
    __shared__ float T[64][65];
    const int tid = threadIdx.x;
#pragma unroll
    for (int it = 0; it < 4; ++it) {
        int idx = tid + it * 256;
        int r = idx >> 4, e4 = (idx & 15) * 4;
        float4 f = *(const float4*)(src + (size_t)(kt * 64 + r) * D + nt * 64 + e4);
        T[r][e4] = f.x; T[r][e4 + 1] = f.y; T[r][e4 + 2] = f.z; T[r][e4 + 3] = f.w;
    }
    __syncthreads();
    ushort* dst = Wt + (size_t)i * D * D + (size_t)(nt * 64) * D + kt * 64;
#pragma unroll
    for (int it = 0; it < 4; ++it) {
        int idx = tid + it * 256;
        int e = idx >> 4, k4 = (idx & 15) * 4;
        ushort4 u;
        u.x = f2b(T[k4][e]); u.y = f2b(T[k4 + 1][e]);
        u.z = f2b(T[k4 + 2][e]); u.w = f2b(T[k4 + 3][e]);
        *(ushort4*)(dst + (size_t)e * D + k4) = u;
    }
}

// fc_W[k][n] (512,513) -> Wt[n][k] bf16, n padded to 576 with zeros
__global__ __launch_bounds__(256) void cvt_fc_k(const float* __restrict__ Wf,
                                                ushort* __restrict__ Wt)
{
    const int nt = blockIdx.x, kt = blockIdx.y;     // 9 x 8
    __shared__ float T[64][65];
    const int tid = threadIdx.x;
#pragma unroll
    for (int it = 0; it < 4; ++it) {
        int idx = tid + it * 256;
        int r = idx >> 4, e4 = (idx & 15) * 4;
#pragma unroll
        for (int j = 0; j < 4; ++j) {
            int n = nt * 64 + e4 + j;
            T[r][e4 + j] = (n < V) ? Wf[(size_t)(kt * 64 + r) * V + n] : 0.f;
        }
    }
    __syncthreads();
    ushort* dst = Wt + (size_t)(nt * 64) * 512 + kt * 64;
#pragma unroll
    for (int it = 0; it < 4; ++it) {
        int idx = tid + it * 256;
        int e = idx >> 4, k4 = (idx & 15) * 4;
        ushort4 u;
        u.x = f2b(T[k4][e]); u.y = f2b(T[k4 + 1][e]);
        u.z = f2b(T[k4 + 2][e]); u.w = f2b(T[k4 + 3][e]);
        *(ushort4*)(dst + (size_t)e * 512 + k4) = u;
    }
}

// ---------------------------------------------------------------------------
// bf16 MFMA GEMM (R13 structure) with global_load_lds(16B) staging:
// per-lane XOR'd GLOBAL source (sc = ((lane&7)^(lane>>3))*8, key = row&7,
// 8-row-aligned groups), LINEAR wave-uniform LDS dest, XOR'd ds_read_b128
// (both-sides involution, validated R7). __syncthreads drains vmcnt before
// fragment reads. A-rows >= BL read adjacent ws buffers; outputs discarded.
// MODE 0: QKV (N=1536): q/k bf16 (B,H,L,HS); v bf16 transposed (B,H,HS,LP).
// MODE 1: MLP (N=512):  o0 fp32 = gelu(acc+bias) + o0 (in-place h).
// MODE 2: FC  (N=576p): o0 fp32 [r*V+c] = acc + bias[c], c < V.
// MODE 3: MLP final:    o0 bf16 = f2b(gelu(acc+bias) + o1[r*D+c]).
// ---------------------------------------------------------------------------
template <int MODE>
__global__ __launch_bounds__(256) void mgemm_k(const ushort* __restrict__ A,
                                               const ushort* __restrict__ Bt,
                                               const float* __restrict__ bias,
                                               void* __restrict__ o0,
                                               void* __restrict__ o1,
                                               void* __restrict__ o2)
{
    __shared__ ushort As[64 * 64] __attribute__((aligned(16)));
    __shared__ ushort Bs[64 * 64] __attribute__((aligned(16)));
    const int tid  = threadIdx.x;
    const int wave = tid >> 6, lane = tid & 63;
    const int row0 = blockIdx.y * 64;
    const int col0 = blockIdx.x * 64;
    const int wr = (wave >> 1) * 32, wc = (wave & 1) * 32;
    const int frow = lane & 15;
    const int kb   = lane >> 4;

    // staging: wave covers rows [wave*16, wave*16+16) in two 8-row issues.
    const int lrow = lane >> 3;                       // 0..7 within group
    const int sc   = ((lane & 7) ^ lrow) * 8;         // XOR'd source chunk

    f32x4 acc[2][2] = {};

    for (int k0 = 0; k0 < 512; k0 += 64) {
#pragma unroll
        for (int j = 0; j < 2; ++j) {
            const int rb = (wave * 2 + j) * 8;        // tile-local row base
            const int r  = rb + lrow;
            gload16(A  + (size_t)(row0 + r) * 512 + k0 + sc, &As[rb * 64]);
            gload16(Bt + (size_t)(col0 + r) * 512 + k0 + sc, &Bs[rb * 64]);
        }
        __syncthreads();                              // drains vmcnt
#pragma unroll
        for (int ks = 0; ks < 2; ++ks) {
            bf16x8 a[2], b[2];
            const int g = ks * 4 + kb;
#pragma unroll
            for (int f = 0; f < 2; ++f) {
                const int ra_ = wr + f * 16 + frow;
                a[f] = *(const bf16x8*)&As[ra_ * 64 + ((g ^ (ra_ & 7)) * 8)];
                const int rb_ = wc + f * 16 + frow;
                b[f] = *(const bf16x8*)&Bs[rb_ * 64 + ((g ^ (rb_ & 7)) * 8)];
            }
#pragma unroll
            for (int fi = 0; fi < 2; ++fi)
#pragma unroll
                for (int fj = 0; fj < 2; ++fj)
                    acc[fi][fj] = __builtin_amdgcn_mfma_f32_16x16x32_bf16(
                        a[fi], b[fj], acc[fi][fj], 0, 0, 0);
        }
        __syncthreads();
    }

    // C frag layout: col = lane&15, row = (lane>>4)*4 + reg
    const int rbase = row0 + wr + (lane >> 4) * 4;
    const int cbase = col0 + wc + (lane & 15);
#pragma unroll
    for (int fi = 0; fi < 2; ++fi) {
#pragma unroll
        for (int fj = 0; fj < 2; ++fj) {
            const int c = cbase + fj * 16;
#pragma unroll
            for (int rg = 0; rg < 4; ++rg) {
                const int r = rbase + fi * 16 + rg;
                if (r >= BL) continue;
                float val = acc[fi][fj][rg];
                if (MODE == 0) {
                    int buf = c >> 9, cc = c & 511;
                    int b_ = r / L, l = r % L;
                    int head = cc >> 6, e = cc & 63;
                    int bh = b_ * H + head;
                    if (buf == 0)
                        ((ushort*)o0)[((size_t)bh * L + l) * HS + e] = f2b(val);
                    else if (buf == 1)
                        ((ushort*)o1)[((size_t)bh * L + l) * HS + e] = f2b(val);
                    else
                        ((ushort*)o2)[((size_t)bh * HS + e) * LP + l] = f2b(val);
                } else if (MODE == 1) {
                    float xv = val + bias[c];
                    float gl = 0.5f * xv * (1.f + erff(xv * 0.70710678118654752f));
                    ((float*)o0)[(size_t)r * D + c] = gl + ((float*)o0)[(size_t)r * D + c];
                } else if (MODE == 3) {
                    float xv = val + bias[c];
                    float gl = 0.5f * xv * (1.f + erff(xv * 0.70710678118654752f));
                    float res = ((const float*)o1)[(size_t)r * D + c];
                    ((ushort*)o0)[(size_t)r * D + c] = f2b(gl + res);
                } else {
                    if (c < V) ((float*)o0)[(size_t)r * V + c] = val + bias[c];
                }
            }
        }
    }
}

// ---------------------------------------------------------------------------
// MFMA flash attention (unchanged from R13 — verified at 544 us).
// ---------------------------------------------------------------------------
__global__ __launch_bounds__(256) void fattn_k(const ushort* __restrict__ qb,
                                               const ushort* __restrict__ kb,
                                               const ushort* __restrict__ vT,
                                               float* __restrict__ hbuf)
{
    __shared__ ushort Qs[64 * 64];
    __shared__ ushort Ks[64 * 64];
    __shared__ ushort Vs[64 * 64];   // [e][kv]
    __shared__ ushort Ps[64][72];

    const int bx  = blockIdx.x;
    const int bh  = bx / 9;
    const int qt  = 8 - (bx % 9);        // big tiles dispatched first
    const int q0  = qt * 64;
    const int tid = threadIdx.x;
    const int wave = tid >> 6, lane = tid & 63;
    const int lg = lane >> 4, li = lane & 15;
    const int wq = wave * 16;

    const int sr0 = tid >> 3, skc = tid & 7;
    const int sr1 = (tid + 256) >> 3;
    const int ss0 = (skc ^ (sr0 & 7)) * 8;
    const int ss1 = (skc ^ (sr1 & 7)) * 8;

    // ---- stage Q (swizzled) ----
    {
        int qr = q0 + sr0;
        uint4 v = make_uint4(0u, 0u, 0u, 0u);
        if (qr < L) v = *(const uint4*)(qb + ((size_t)bh * L + qr) * HS + skc * 8);
        *(uint4*)&Qs[sr0 * 64 + ss0] = v;
        qr = q0 + sr1;
        v = make_uint4(0u, 0u, 0u, 0u);
        if (qr < L) v = *(const uint4*)(qb + ((size_t)bh * L + qr) * HS + skc * 8);
        *(uint4*)&Qs[sr1 * 64 + ss1] = v;
    }

    const short one_b = (short)0x3F80;                 // bf16 1.0
    const bf16x8 ones = { one_b, one_b, one_b, one_b, one_b, one_b, one_b, one_b };

    f32x4 accO[4] = {};
    f32x4 accL = {};

    const int n_mt = qt + 1;
    uint4 kr[2], vr[2];

    auto loadKV = [&](int t) {
        int mr = t * 64 + sr0;
        kr[0] = make_uint4(0u, 0u, 0u, 0u);
        if (mr < L) kr[0] = *(const uint4*)(kb + ((size_t)bh * L + mr) * HS + skc * 8);
        vr[0] = *(const uint4*)(vT + ((size_t)bh * HS + sr0) * LP + t * 64 + skc * 8);
        mr = t * 64 + sr1;
        kr[1] = make_uint4(0u, 0u, 0u, 0u);
        if (mr < L) kr[1] = *(const uint4*)(kb + ((size_t)bh * L + mr) * HS + skc * 8);
        vr[1] = *(const uint4*)(vT + ((size_t)bh * HS + sr1) * LP + t * 64 + skc * 8);
    };
    auto writeKV = [&]() {
        *(uint4*)&Ks[sr0 * 64 + ss0] = kr[0];
        *(uint4*)&Vs[sr0 * 64 + ss0] = vr[0];
        *(uint4*)&Ks[sr1 * 64 + ss1] = kr[1];
        *(uint4*)&Vs[sr1 * 64 + ss1] = vr[1];
    };

    loadKV(0);
    writeKV();
    __syncthreads();

    for (int t = 0; t < n_mt; ++t) {
        if (t + 1 < n_mt) loadKV(t + 1);    // issue early (hidden under compute)

        // ---- S = Q K^T ----
        f32x4 accS[4] = {};
#pragma unroll
        for (int ks = 0; ks < 2; ++ks) {
            const int g = ks * 4 + lg;
            const int ra_ = wq + li;
            bf16x8 a = *(const bf16x8*)&Qs[ra_ * 64 + ((g ^ (ra_ & 7)) * 8)];
#pragma unroll
            for (int j = 0; j < 4; ++j) {
                const int rb_ = j * 16 + li;
                bf16x8 b = *(const bf16x8*)&Ks[rb_ * 64 + ((g ^ (rb_ & 7)) * 8)];
                accS[j] = __builtin_amdgcn_mfma_f32_16x16x32_bf16(a, b, accS[j], 0, 0, 0);
            }
        }

        // ---- P = exp(S/8) masked; write Ps ----
        const int m0 = t * 64;
#pragma unroll
        for (int rg = 0; rg < 4; ++rg) {
            const int qrow = q0 + wq + lg * 4 + rg;
#pragma unroll
            for (int j = 0; j < 4; ++j) {
                int mcol = m0 + j * 16 + li;
                float p = (mcol > qrow || mcol >= L) ? 0.f : __expf(accS[j][rg] * 0.125f);
                Ps[wq + lg * 4 + rg][j * 16 + li] = f2b(p);
            }
        }

        // ---- O += P V ; L += P 1 ----
#pragma unroll
        for (int ks = 0; ks < 2; ++ks) {
            bf16x8 a = *(const bf16x8*)&Ps[wq + li][ks * 32 + lg * 8];
            accL = __builtin_amdgcn_mfma_f32_16x16x32_bf16(a, ones, accL, 0, 0, 0);
#pragma unroll
            for (int j = 0; j < 4; ++j) {
                const int g = ks * 4 + lg;
                const int rb_ = j * 16 + li;
                bf16x8 b = *(const bf16x8*)&Vs[rb_ * 64 + ((g ^ (rb_ & 7)) * 8)];
                accO[j] = __builtin_amdgcn_mfma_f32_16x16x32_bf16(a, b, accO[j], 0, 0, 0);
            }
        }
        __syncthreads();                    // done reading Ks/Vs
        if (t + 1 < n_mt) {
            writeKV();                      // vmcnt wait lands here
            __syncthreads();
        }
    }

    // ---- epilogue: h += O / L ----
    const int b_ = bh / H, hh = bh % H;
#pragma unroll
    for (int rg = 0; rg < 4; ++rg) {
        const int qrow = q0 + wq + lg * 4 + rg;
        if (qrow >= L) continue;
        const float inv = 1.f / accL[rg];
        float* dst = hbuf + ((size_t)b_ * L + qrow) * D + hh * HS;
#pragma unroll
        for (int j = 0; j < 4; ++j)
            dst[j * 16 + li] += accO[j][rg] * inv;
    }
}

// ---------------------------------------------------------------------------
extern "C" void kernel_launch(void* const* d_in, const int* in_sizes, int n_in,
                              void* d_out, int out_size, void* d_ws, size_t ws_size,
                              hipStream_t stream)
{
    const int*   x    = (const int*)d_in[0];
    const float* emb  = (const float*)d_in[1];
    const float* pos  = (const float*)d_in[2];
    const float* Wq   = (const float*)d_in[3];
    const float* Wk   = (const float*)d_in[4];
    const float* Wv   = (const float*)d_in[5];
    const float* ln1g = (const float*)d_in[6];
    const float* ln1b = (const float*)d_in[7];
    const float* ln2g = (const float*)d_in[8];
    const float* ln2b = (const float*)d_in[9];
    const float* mlpW = (const float*)d_in[10];
    const float* mlpb = (const float*)d_in[11];
    const float* fcW  = (const float*)d_in[12];
    const float* fcb  = (const float*)d_in[13];
    float* out = (float*)d_out;

    // workspace layout — all 16B aligned. NOTE: xnb and hb are followed by
    // other buffers so mgemm's unguarded tail reads (rows >= BL) stay in-ws.
    char* ws = (char*)d_ws;
    float*  h   = (float*)ws;    ws += (size_t)BL * D * 4;
    ushort* qb  = (ushort*)ws;   ws += (size_t)BL * D * 2;
    ushort* kbuf= (ushort*)ws;   ws += (size_t)BL * D * 2;
    ushort* vT  = (ushort*)ws;   ws += (size_t)B * H * HS * LP * 2;
    ushort* xnb = (ushort*)ws;   ws += (size_t)BL * D * 2;
    ushort* hb  = (ushort*)ws;   ws += (size_t)BL * D * 2;
    ushort* Wp  = (ushort*)ws;   ws += (size_t)NL * 1536 * 512 * 2;
    ushort* Wtm = (ushort*)ws;   ws += (size_t)NL * D * D * 2;
    ushort* Wtf = (ushort*)ws;   ws += (size_t)576 * 512 * 2;

    cvt_qkv_k<<<dim3(8, NL * H, 3), 256, 0, stream>>>(Wq, Wk, Wv, Wp);
    cvt_mlp_k<<<dim3(8, 8, NL), 256, 0, stream>>>(mlpW, Wtm);
    cvt_fc_k<<<dim3(9, 8), 256, 0, stream>>>(fcW, Wtf);

    for (int i = 0; i < NL; ++i) {
        if (i == 0)
            ln_embed4_k<<<BL / 4, 256, 0, stream>>>(x, emb, pos, ln1g, ln1b, h, xnb);
        else
            ln4_k<<<BL / 4, 256, 0, stream>>>(h, ln1g + i * D, ln1b + i * D, xnb);
        mgemm_k<0><<<dim3(24, 65), 256, 0, stream>>>(
            xnb, Wp + (size_t)i * 1536 * 512, nullptr, qb, kbuf, vT);
        fattn_k<<<B * H * 9, 256, 0, stream>>>(qb, kbuf, vT, h);
        ln4_k<<<BL / 4, 256, 0, stream>>>(h, ln2g + i * D, ln2b + i * D, xnb);
        if (i < NL - 1)
            mgemm_k<1><<<dim3(8, 65), 256, 0, stream>>>(
                xnb, Wtm + (size_t)i * D * D, mlpb + i * D, h, nullptr, nullptr);
        else
            mgemm_k<3><<<dim3(8, 65), 256, 0, stream>>>(
                xnb, Wtm + (size_t)i * D * D, mlpb + i * D, hb, h, nullptr);
    }
    mgemm_k<2><<<dim3(9, 65), 256, 0, stream>>>(hb, Wtf, fcb, out, nullptr, nullptr);
}